// Round 3
// baseline (359.519 us; speedup 1.0000x reference)
//
#include <hip/hip_runtime.h>

// EdgeDecoder: out[e] = w2 . relu(W1 @ concat(z_sotu[row[e]], z_taxon[col[e]]) + b1) + b2
// E=1e6, H=128, K=2H=256. fp32 inputs, int32 indices, fp32 output.
//
// Round 3: two-phase.
//  Phase 1 (convert_kernel, mem-bound ~20us): z_sotu, z_taxon, w1 fp32 -> bf16 into d_ws.
//    Removes ~1000 VALU instrs/thread of repeated RNE conversion from the hot kernel
//    (each z row converted ~10x, w1 converted 7813x in round 2).
//  Phase 2 (edge_mlp_kernel): gather bf16 rows straight into LDS via
//    global_load_lds width=16 (no VGPR round-trip, half the gathered bytes),
//    XOR-swizzled; K-loop/epilogue identical to the round-2 proven code.
//  Fallback: if ws_size < 38.5 MB, run the round-2 fused kernel (proven correct).
//
// GEMM: C[M=128 hidden][N=128 edges/block] = W1 @ Z^T, mfma_f32_32x32x16_bf16.
// Edges on N: C-layout col=lane&31=edge -> layer-2 is an in-lane reduce.
// Wave w owns hidden rows [32w,32w+32): A-frags persistent in 64 VGPRs.
// LDS 64 KB -> 2 blocks/CU; resident-block overlap hides staging latency.

#define HID    128
#define KDIM   256
#define TILE_E 128

typedef __attribute__((ext_vector_type(8)))  short  bf16x8;   // 8 bf16 = 4 VGPRs
typedef __attribute__((ext_vector_type(16))) float  f32x16;   // 32x32 MFMA accumulator

__device__ __forceinline__ unsigned short f2bf(float f) {
    unsigned u = __float_as_uint(f);
    u += 0x7fffu + ((u >> 16) & 1u);   // round-to-nearest-even
    return (unsigned short)(u >> 16);
}

__device__ __forceinline__ bf16x8 pack8(float4 a, float4 b) {
    bf16x8 f;
    f[0] = (short)f2bf(a.x); f[1] = (short)f2bf(a.y);
    f[2] = (short)f2bf(a.z); f[3] = (short)f2bf(a.w);
    f[4] = (short)f2bf(b.x); f[5] = (short)f2bf(b.y);
    f[6] = (short)f2bf(b.z); f[7] = (short)f2bf(b.w);
    return f;
}

// ---------------- Phase 1: fp32 -> bf16 bulk convert (grid-stride over 3 regions)
__global__ __launch_bounds__(256)
void convert_kernel(const float* __restrict__ s, const float* __restrict__ t,
                    const float* __restrict__ w,
                    unsigned short* __restrict__ os, unsigned short* __restrict__ ot,
                    unsigned short* __restrict__ ow,
                    long long ES, long long ET, long long EW)
{
    const long long i8 = ((long long)blockIdx.x * 256 + threadIdx.x) * 8;
    const long long total = ES + ET + EW;        // all divisible by 8
    if (i8 >= total) return;
    const float* src; unsigned short* dst; long long off;
    if (i8 < ES)           { src = s; dst = os; off = i8; }
    else if (i8 < ES + ET) { src = t; dst = ot; off = i8 - ES; }
    else                   { src = w; dst = ow; off = i8 - ES - ET; }
    const float4 a = *(const float4*)(src + off);
    const float4 b = *(const float4*)(src + off + 4);
    *(bf16x8*)(dst + off) = pack8(a, b);
}

// ---------------- Phase 2: hot kernel, bf16 gather via global_load_lds
__global__ __launch_bounds__(256, 2)
void edge_mlp_kernel(const unsigned short* __restrict__ zsb,  // [100000,128] bf16
                     const unsigned short* __restrict__ ztb,  // [50000,128] bf16
                     const int*   __restrict__ row,           // [E] int32
                     const int*   __restrict__ col,           // [E] int32
                     const unsigned short* __restrict__ w1b,  // [128,256] bf16
                     const float* __restrict__ b1,            // [128] fp32
                     const float* __restrict__ w2,            // [128] fp32
                     const float* __restrict__ b2,            // [1]  fp32
                     float*       __restrict__ out,           // [E] fp32
                     int E)
{
    __shared__ __align__(16) unsigned short zs[TILE_E * KDIM];   // 64 KB bf16, swizzled

    const int tid  = threadIdx.x;
    const int wave = tid >> 6;
    const int lane = tid & 63;
    const int l31  = lane & 31;
    const int hlf  = lane >> 5;
    const long long e0 = (long long)blockIdx.x * TILE_E;

    // ---- Stage Z tile: wave w stages tile rows [32w, 32w+32), 2 rows (1 KB) per
    // global_load_lds issue (dest = uniform base + lane*16). Lane i -> row
    // r = 32w+2j+(i>>5), LDS chunk pos p = i&31, source chunk c = p ^ (r&31).
    // Chunks 0..15 = sotu half (k 0..127), 16..31 = taxon half (k 128..255).
    #pragma unroll
    for (int j = 0; j < 16; ++j) {
        const int r = 32 * wave + 2 * j + hlf;
        const int c = l31 ^ (r & 31);
        long long e = e0 + r;
        if (e >= E) e = E - 1;                  // tail clamp (store is guarded)
        const unsigned short* g = (c < 16)
            ? zsb + (long long)row[e] * HID + c * 8
            : ztb + (long long)col[e] * HID + (c - 16) * 8;
        __builtin_amdgcn_global_load_lds(
            (const __attribute__((address_space(1))) void*)g,
            (__attribute__((address_space(3))) void*)(zs + (32 * wave + 2 * j) * KDIM),
            16, 0, 0);
    }

    // ---- W1 A-frags (bf16, L2-hot; independent of LDS — overlaps DMA latency).
    // A layout: lane holds A[m=lane&31][k = hlf*8 + j]; frag ks covers k = 16*ks..+16.
    bf16x8 afrag[16];
    {
        const unsigned short* wrow = w1b + (32 * wave + l31) * KDIM + hlf * 8;
        #pragma unroll
        for (int ks = 0; ks < 16; ++ks)
            afrag[ks] = *(const bf16x8*)(wrow + ks * 16);
    }
    __syncthreads();   // drains vmcnt (DMA) before barrier

    // ---- K-loop: 4 edge n-tiles x 16 k-steps. B layout: lane holds B[n=lane&31][k=hlf*8+j].
    f32x16 acc[4] = {};
    #pragma unroll
    for (int ks = 0; ks < 16; ++ks) {
        #pragma unroll
        for (int nt = 0; nt < 4; ++nt) {
            const int el = 32 * nt + l31;                 // edge slot within tile
            const int q  = (2 * ks + hlf) ^ l31;          // swizzled chunk position
            bf16x8 bfrag = *(const bf16x8*)(zs + el * KDIM + q * 8);
            acc[nt] = __builtin_amdgcn_mfma_f32_32x32x16_bf16(afrag[ks], bfrag, acc[nt], 0, 0, 0);
        }
    }

    __syncthreads();                  // all b-frag reads done before aliasing zs
    float* partial = (float*)zs;      // [4][TILE_E] cross-wave partials (2 KB)

    // b1/w2 for this lane's 16 hidden rows: hid = 32w + (r&3) + 8*(r>>2) + 4*hlf
    float b1v[16], w2v[16];
    #pragma unroll
    for (int g = 0; g < 4; ++g) {
        const int hb = 32 * wave + 8 * g + 4 * hlf;
        const float4 bb = *(const float4*)(b1 + hb);
        const float4 ww = *(const float4*)(w2 + hb);
        b1v[4*g+0] = bb.x; b1v[4*g+1] = bb.y; b1v[4*g+2] = bb.z; b1v[4*g+3] = bb.w;
        w2v[4*g+0] = ww.x; w2v[4*g+1] = ww.y; w2v[4*g+2] = ww.z; w2v[4*g+3] = ww.w;
    }

    // Lane holds 16 hidden of edge (32*nt + l31); mirror lane (^32) holds the
    // complementary 16 of the SAME edge -> one shfl_xor completes the 32-hid slice.
    #pragma unroll
    for (int nt = 0; nt < 4; ++nt) {
        float p = 0.0f;
        #pragma unroll
        for (int r = 0; r < 16; ++r) {
            const float h = fmaxf(acc[nt][r] + b1v[r], 0.0f);
            p = fmaf(h, w2v[r], p);
        }
        p += __shfl_xor(p, 32, 64);
        if (hlf == 0)
            partial[wave * TILE_E + 32 * nt + l31] = p;
    }
    __syncthreads();

    if (tid < TILE_E) {
        const long long e = e0 + tid;
        if (e < E) {
            out[e] = partial[0 * TILE_E + tid] + partial[1 * TILE_E + tid]
                   + partial[2 * TILE_E + tid] + partial[3 * TILE_E + tid]
                   + b2[0];
        }
    }
}

// ---------------- Fallback: round-2 proven fused kernel (used only if ws too small)
__global__ __launch_bounds__(256, 2)
void edge_mlp_fused(const float* __restrict__ z_sotu, const float* __restrict__ z_taxon,
                    const int* __restrict__ row, const int* __restrict__ col,
                    const float* __restrict__ w1, const float* __restrict__ b1,
                    const float* __restrict__ w2, const float* __restrict__ b2,
                    float* __restrict__ out, int E)
{
    __shared__ __align__(16) unsigned short zs[TILE_E * KDIM];
    const int tid  = threadIdx.x;
    const int wave = tid >> 6;
    const int lane = tid & 63;
    const int l31  = lane & 31;
    const int hlf  = lane >> 5;
    const long long e0 = (long long)blockIdx.x * TILE_E;
    {
        const int ch  = lane & 15;
        const int rhl = lane >> 4;
        #pragma unroll
        for (int pass = 0; pass < 16; ++pass) {
            const int rh = pass * 4 + rhl;
            const int r  = 32 * wave + (rh >> 1);
            const int hh = rh & 1;
            long long e = e0 + r;
            if (e >= E) e = E - 1;
            const int idx = hh ? col[e] : row[e];
            const float* src = (hh ? z_taxon : z_sotu) + (long long)idx * HID + ch * 8;
            const float4 a = *(const float4*)(src);
            const float4 b = *(const float4*)(src + 4);
            const int c = hh * 16 + ch;
            const int q = c ^ (r & 31);
            *(bf16x8*)(zs + r * KDIM + q * 8) = pack8(a, b);
        }
    }
    bf16x8 afrag[16];
    {
        const float* wrow = w1 + (32 * wave + l31) * KDIM + hlf * 8;
        #pragma unroll
        for (int ks = 0; ks < 16; ++ks) {
            const float4 a = *(const float4*)(wrow + ks * 16);
            const float4 b = *(const float4*)(wrow + ks * 16 + 4);
            afrag[ks] = pack8(a, b);
        }
    }
    __syncthreads();
    f32x16 acc[4] = {};
    #pragma unroll
    for (int ks = 0; ks < 16; ++ks) {
        #pragma unroll
        for (int nt = 0; nt < 4; ++nt) {
            const int el = 32 * nt + l31;
            const int q  = (2 * ks + hlf) ^ l31;
            bf16x8 bfrag = *(const bf16x8*)(zs + el * KDIM + q * 8);
            acc[nt] = __builtin_amdgcn_mfma_f32_32x32x16_bf16(afrag[ks], bfrag, acc[nt], 0, 0, 0);
        }
    }
    __syncthreads();
    float* partial = (float*)zs;
    float b1v[16], w2v[16];
    #pragma unroll
    for (int g = 0; g < 4; ++g) {
        const int hb = 32 * wave + 8 * g + 4 * hlf;
        const float4 bb = *(const float4*)(b1 + hb);
        const float4 ww = *(const float4*)(w2 + hb);
        b1v[4*g+0] = bb.x; b1v[4*g+1] = bb.y; b1v[4*g+2] = bb.z; b1v[4*g+3] = bb.w;
        w2v[4*g+0] = ww.x; w2v[4*g+1] = ww.y; w2v[4*g+2] = ww.z; w2v[4*g+3] = ww.w;
    }
    #pragma unroll
    for (int nt = 0; nt < 4; ++nt) {
        float p = 0.0f;
        #pragma unroll
        for (int r = 0; r < 16; ++r) {
            const float h = fmaxf(acc[nt][r] + b1v[r], 0.0f);
            p = fmaf(h, w2v[r], p);
        }
        p += __shfl_xor(p, 32, 64);
        if (hlf == 0)
            partial[wave * TILE_E + 32 * nt + l31] = p;
    }
    __syncthreads();
    if (tid < TILE_E) {
        const long long e = e0 + tid;
        if (e < E) {
            out[e] = partial[0 * TILE_E + tid] + partial[1 * TILE_E + tid]
                   + partial[2 * TILE_E + tid] + partial[3 * TILE_E + tid]
                   + b2[0];
        }
    }
}

extern "C" void kernel_launch(void* const* d_in, const int* in_sizes, int n_in,
                              void* d_out, int out_size, void* d_ws, size_t ws_size,
                              hipStream_t stream) {
    const float* z_sotu  = (const float*)d_in[0];
    const float* z_taxon = (const float*)d_in[1];
    const int*   row     = (const int*)d_in[2];
    const int*   col     = (const int*)d_in[3];
    const float* w1      = (const float*)d_in[4];
    const float* b1      = (const float*)d_in[5];
    const float* w2      = (const float*)d_in[6];
    const float* b2      = (const float*)d_in[7];
    float*       out     = (float*)d_out;

    const long long ES = in_sizes[0];   // 12,800,000
    const long long ET = in_sizes[1];   //  6,400,000
    const long long EW = in_sizes[4];   //     32,768
    const int E = in_sizes[2];
    const int nblocks = (E + TILE_E - 1) / TILE_E;
    const size_t need = (size_t)(ES + ET + EW) * 2;

    if (ws_size >= need) {
        unsigned short* zsb = (unsigned short*)d_ws;
        unsigned short* ztb = zsb + ES;
        unsigned short* w1b = ztb + ET;
        const long long total8 = (ES + ET + EW) / 8;
        const int cblocks = (int)((total8 + 255) / 256);
        hipLaunchKernelGGL(convert_kernel, dim3(cblocks), dim3(256), 0, stream,
                           z_sotu, z_taxon, w1, zsb, ztb, w1b, ES, ET, EW);
        hipLaunchKernelGGL(edge_mlp_kernel, dim3(nblocks), dim3(256), 0, stream,
                           zsb, ztb, row, col, w1b, b1, w2, b2, out, E);
    } else {
        hipLaunchKernelGGL(edge_mlp_fused, dim3(nblocks), dim3(256), 0, stream,
                           z_sotu, z_taxon, row, col, w1, b1, w2, b2, out, E);
    }
}